// Round 10
// baseline (1513.651 us; speedup 1.0000x reference)
//
#include <hip/hip_runtime.h>
#include <hip/hip_bf16.h>

#define NN 50000
#define NE 800000
#define NG 512
#define DD 128
#define MM 256
#define TT 4
#define NPASS 4
#define GHID 256
#define NKEY (NN * TT)          // CSR keys: src*4 + type

typedef __bf16 bf16x2 __attribute__((ext_vector_type(2)));
typedef __bf16 bf16x8 __attribute__((ext_vector_type(8)));
typedef float f32x4 __attribute__((ext_vector_type(4)));

// ================= setup: swizzled weights =================
// WK: msgs GEMM B, K=512 in 16 chunks: WK[((c*4+lq)*256+col)*8+j] = W_msg[((c*4+lq)*8+j)*256+col]
__global__ void build_WK(const float* __restrict__ W_msg, __bf16* __restrict__ WK) {
    int i = blockIdx.x * 256 + threadIdx.x;           // 131072
    if (i >= 16 * 4 * 256 * 8) return;
    int j = i & 7, col = (i >> 3) & 255, g = i >> 11; // g=c*4+lq
    int k = g * 8 + j;
    WK[i] = (__bf16)W_msg[k * 256 + col];
}

// WB: 512 cols x K=384 (12 chunks). cols [0,128)=r, [128,256)=z (Wih+Whh stacked over k),
// [256,384)=i_n (Wih only), [384,512)=h_n (Whh only). k<256 -> msgs, k>=256 -> hb.
__global__ void build_WB(const float* __restrict__ W_ih, const float* __restrict__ W_hh,
                         __bf16* __restrict__ WB) {
    int i = blockIdx.x * 256 + threadIdx.x;           // 196608
    if (i >= 12 * 4 * 512 * 8) return;
    int j = i & 7, col = (i >> 3) & 511, g = i >> 12; // g=c*4+lq
    int k = g * 8 + j;                                // 0..383
    float v = 0.f;
    if (col < 256) {
        v = (k < 256) ? W_ih[col * 256 + k] : W_hh[col * 128 + (k - 256)];
    } else if (col < 384) {
        if (k < 256) v = W_ih[col * 256 + k];
    } else {
        if (k >= 256) v = W_hh[(col - 128) * 128 + (k - 256)];
    }
    WB[i] = (__bf16)v;
}

__global__ void build_bias512(const float* __restrict__ b_ih, const float* __restrict__ b_hh,
                              float* __restrict__ b512) {
    int c = blockIdx.x * 256 + threadIdx.x;
    if (c >= 512) return;
    float v;
    if (c < 256) v = b_ih[c] + b_hh[c];
    else if (c < 384) v = b_ih[c];
    else v = b_hh[c - 128];
    b512[c] = v;
}

// ================= embedding =================
__global__ void embed_kernel(const int* __restrict__ node_types,
                             const float* __restrict__ emb,
                             float* __restrict__ hf, __bf16* __restrict__ hb) {
    int t = blockIdx.x * 256 + threadIdx.x;
    if (t >= NN * DD) return;
    int node = t >> 7, d = t & 127;
    float v = emb[node_types[node] * DD + d];
    hf[t] = v;
    hb[t] = (__bf16)v;
}

// ================= CSR build (keyed by src*4+type) =================
__global__ void hist_kernel(const int* __restrict__ src, const int* __restrict__ et,
                            int* __restrict__ counts) {
    int e = blockIdx.x * 256 + threadIdx.x;
    if (e < NE) atomicAdd(&counts[src[e] * TT + et[e]], 1);
}

__global__ void ghist_kernel(const int* __restrict__ n2g, int* __restrict__ gcounts) {
    int i = blockIdx.x * 256 + threadIdx.x;
    if (i < NN) atomicAdd(&gcounts[n2g[i]], 1);
}

__global__ void scan1(const int* __restrict__ counts, int* __restrict__ offsets,
                      int* __restrict__ bsum, int n) {
    __shared__ int sm[256];
    int i = blockIdx.x * 256 + threadIdx.x;
    int v = (i < n) ? counts[i] : 0;
    sm[threadIdx.x] = v;
    __syncthreads();
    for (int off = 1; off < 256; off <<= 1) {
        int t = (threadIdx.x >= off) ? sm[threadIdx.x - off] : 0;
        __syncthreads();
        sm[threadIdx.x] += t;
        __syncthreads();
    }
    if (i < n) offsets[i] = sm[threadIdx.x] - v;
    if (threadIdx.x == 255) bsum[blockIdx.x] = sm[255];
}

__global__ void scan2(int* __restrict__ bsum, int nb, int* __restrict__ offsets, int n) {
    __shared__ int sm[1024];
    int v = (threadIdx.x < nb) ? bsum[threadIdx.x] : 0;
    sm[threadIdx.x] = v;
    __syncthreads();
    for (int off = 1; off < 1024; off <<= 1) {
        int t = (threadIdx.x >= off) ? sm[threadIdx.x - off] : 0;
        __syncthreads();
        sm[threadIdx.x] += t;
        __syncthreads();
    }
    if (threadIdx.x < nb) bsum[threadIdx.x] = sm[threadIdx.x] - v;
    if (threadIdx.x == 1023) offsets[n] = sm[1023];
}

__global__ void scan3(int* __restrict__ offsets, const int* __restrict__ bsum,
                      int* __restrict__ cursor, int n) {
    int i = blockIdx.x * 256 + threadIdx.x;
    if (i < n) {
        int o = offsets[i] + bsum[blockIdx.x];
        offsets[i] = o;
        if (cursor) cursor[i] = o;
    }
}

__global__ void fill_kernel(const int* __restrict__ src, const int* __restrict__ dst,
                            const int* __restrict__ et, int* __restrict__ cursor,
                            int* __restrict__ elist) {
    int e = blockIdx.x * 256 + threadIdx.x;
    if (e >= NE) return;
    int pos = atomicAdd(&cursor[src[e] * TT + et[e]], 1);
    elist[pos] = dst[e];
}

// ================= aggregation: wave per key, 8 concurrent gathers =================
__global__ void agg4(const int* __restrict__ offsets, const int* __restrict__ elist,
                     const __bf16* __restrict__ hb, __bf16* __restrict__ X) {
    int w = blockIdx.x * 4 + (threadIdx.x >> 6);
    if (w >= NKEY) return;
    int lane = threadIdx.x & 63;
    int beg = offsets[w], end = offsets[w + 1];
    float ax = 0.f, ay = 0.f;
    for (int base = beg; base < end; base += 8) {
        int nb = end - base; if (nb > 8) nb = 8;          // wave-uniform
        int idx = (lane < nb) ? elist[base + lane] : 0;
        int i0 = __shfl(idx, 0), i1 = __shfl(idx, 1), i2 = __shfl(idx, 2), i3 = __shfl(idx, 3);
        int i4 = __shfl(idx, 4), i5 = __shfl(idx, 5), i6 = __shfl(idx, 6), i7 = __shfl(idx, 7);
        size_t col = lane * 2;
        bf16x2 v0, v1, v2, v3, v4, v5, v6, v7;
        v0 = *(const bf16x2*)(hb + (size_t)i0 * DD + col);
        if (nb > 1) v1 = *(const bf16x2*)(hb + (size_t)i1 * DD + col);
        if (nb > 2) v2 = *(const bf16x2*)(hb + (size_t)i2 * DD + col);
        if (nb > 3) v3 = *(const bf16x2*)(hb + (size_t)i3 * DD + col);
        if (nb > 4) v4 = *(const bf16x2*)(hb + (size_t)i4 * DD + col);
        if (nb > 5) v5 = *(const bf16x2*)(hb + (size_t)i5 * DD + col);
        if (nb > 6) v6 = *(const bf16x2*)(hb + (size_t)i6 * DD + col);
        if (nb > 7) v7 = *(const bf16x2*)(hb + (size_t)i7 * DD + col);
        ax += (float)v0.x; ay += (float)v0.y;
        if (nb > 1) { ax += (float)v1.x; ay += (float)v1.y; }
        if (nb > 2) { ax += (float)v2.x; ay += (float)v2.y; }
        if (nb > 3) { ax += (float)v3.x; ay += (float)v3.y; }
        if (nb > 4) { ax += (float)v4.x; ay += (float)v4.y; }
        if (nb > 5) { ax += (float)v5.x; ay += (float)v5.y; }
        if (nb > 6) { ax += (float)v6.x; ay += (float)v6.y; }
        if (nb > 7) { ax += (float)v7.x; ay += (float)v7.y; }
    }
    bf16x2 o; o.x = (__bf16)ax; o.y = (__bf16)ay;
    *(bf16x2*)(X + (size_t)w * 128 + lane * 2) = o;
}

// ================= fused msgs+GRU GEMM with LDS weight staging =================
// grid 782 x 256 thr (4 waves, 64 rows). Phase 1: msgs tile = relu(X@WK+bias) -> wave-private
// LDS (WK chunks staged cooperatively). Phase 2: c-outer GRU GEMM, WB chunks staged, 32 acc.
__global__ void mg_gemm2(const __bf16* __restrict__ X, const __bf16* __restrict__ WK,
                         const __bf16* __restrict__ WB, const float* __restrict__ b_msg,
                         const float* __restrict__ b512, const int* __restrict__ offsets,
                         const __bf16* __restrict__ hbc, float* __restrict__ hf,
                         __bf16* __restrict__ hbn) {
    __shared__ __bf16 Ms[4][16][264];   // 33 KB wave-private msgs tiles (264: 16B-aligned rows, 2-way max)
    __shared__ __bf16 Ws[16384];        // 32 KB weight-chunk stage
    int tid = threadIdx.x, wave = tid >> 6, lane = tid & 63;
    int lm = lane & 15, lq = lane >> 4;
    int r0 = blockIdx.x * 64 + wave * 16;
    int arow = r0 + lm; if (arow >= NN) arow = NN - 1;

    // ---- phase 1: msgs tile (K=512, 16 chunks; WK chunk = 8192 elems staged) ----
    {
        const __bf16* Ap = X + (size_t)arow * 512 + lq * 8;
        f32x4 acc[16] = {};
        for (int c = 0; c < 16; ++c) {
            const __bf16* src = WK + (size_t)c * 8192;
            bf16x8 t0 = *(const bf16x8*)(src + tid * 8);
            bf16x8 t1 = *(const bf16x8*)(src + 2048 + tid * 8);
            bf16x8 t2 = *(const bf16x8*)(src + 4096 + tid * 8);
            bf16x8 t3 = *(const bf16x8*)(src + 6144 + tid * 8);
            bf16x8 a = *(const bf16x8*)(Ap + c * 32);
            __syncthreads();               // prev chunk consumed
            *(bf16x8*)&Ws[tid * 8]        = t0;
            *(bf16x8*)&Ws[2048 + tid * 8] = t1;
            *(bf16x8*)&Ws[4096 + tid * 8] = t2;
            *(bf16x8*)&Ws[6144 + tid * 8] = t3;
            __syncthreads();               // chunk visible
#pragma unroll
            for (int nt = 0; nt < 16; ++nt) {
                bf16x8 b = *(const bf16x8*)&Ws[((size_t)lq * 256 + nt * 16 + lm) * 8];
                acc[nt] = __builtin_amdgcn_mfma_f32_16x16x32_bf16(a, b, acc[nt], 0, 0, 0);
            }
        }
#pragma unroll
        for (int i = 0; i < 4; ++i) {
            int row = r0 + lq * 4 + i;
            int rowc = (row < NN) ? row : NN - 1;
            int ob = rowc * TT;
            int o0 = offsets[ob], o1 = offsets[ob + 1], o2 = offsets[ob + 2],
                o3 = offsets[ob + 3], o4 = offsets[ob + 4];
            float n0 = (float)(o1 - o0), n1 = (float)(o2 - o1),
                  n2 = (float)(o3 - o2), n3 = (float)(o4 - o3);
#pragma unroll
            for (int nt = 0; nt < 16; ++nt) {
                int col = nt * 16 + lm;
                float bias = n0 * b_msg[col] + n1 * b_msg[MM + col]
                           + n2 * b_msg[2 * MM + col] + n3 * b_msg[3 * MM + col];
                Ms[wave][lq * 4 + i][col] = (__bf16)fmaxf(acc[nt][i] + bias, 0.f);
            }
        }
    }

    // ---- phase 2: GRU GEMM, c-outer (12 chunks; WB chunk = 16384 elems staged), 32 acc ----
    bf16x8 ahb[4];
    {
        const __bf16* Ah = hbc + (size_t)arow * DD + lq * 8;
#pragma unroll
        for (int c4 = 0; c4 < 4; ++c4) ahb[c4] = *(const bf16x8*)(Ah + c4 * 32);
    }
    f32x4 acc2[32] = {};   // [gate g][j]: g*8+j
    for (int c = 0; c < 12; ++c) {
        const __bf16* src = WB + (size_t)c * 16384;
        bf16x8 t0 = *(const bf16x8*)(src + tid * 8);
        bf16x8 t1 = *(const bf16x8*)(src + 2048 + tid * 8);
        bf16x8 t2 = *(const bf16x8*)(src + 4096 + tid * 8);
        bf16x8 t3 = *(const bf16x8*)(src + 6144 + tid * 8);
        bf16x8 t4 = *(const bf16x8*)(src + 8192 + tid * 8);
        bf16x8 t5 = *(const bf16x8*)(src + 10240 + tid * 8);
        bf16x8 t6 = *(const bf16x8*)(src + 12288 + tid * 8);
        bf16x8 t7 = *(const bf16x8*)(src + 14336 + tid * 8);
        bf16x8 a = (c < 8) ? *(const bf16x8*)&Ms[wave][lm][c * 32 + lq * 8] : ahb[c - 8];
        __syncthreads();
        *(bf16x8*)&Ws[tid * 8]         = t0;
        *(bf16x8*)&Ws[2048 + tid * 8]  = t1;
        *(bf16x8*)&Ws[4096 + tid * 8]  = t2;
        *(bf16x8*)&Ws[6144 + tid * 8]  = t3;
        *(bf16x8*)&Ws[8192 + tid * 8]  = t4;
        *(bf16x8*)&Ws[10240 + tid * 8] = t5;
        *(bf16x8*)&Ws[12288 + tid * 8] = t6;
        *(bf16x8*)&Ws[14336 + tid * 8] = t7;
        __syncthreads();
#pragma unroll
        for (int j = 0; j < 8; ++j) {
#pragma unroll
            for (int g = 0; g < 4; ++g) {
                bf16x8 b = *(const bf16x8*)&Ws[((size_t)lq * 512 + g * 128 + j * 16 + lm) * 8];
                acc2[g * 8 + j] = __builtin_amdgcn_mfma_f32_16x16x32_bf16(a, b, acc2[g * 8 + j], 0, 0, 0);
            }
        }
    }
    // ---- epilogue: GRU gates ----
#pragma unroll
    for (int j = 0; j < 8; ++j) {
        int d = j * 16 + lm;
        float cbr = b512[d], cbz = b512[128 + d], cbn = b512[256 + d], cbh = b512[384 + d];
#pragma unroll
        for (int i = 0; i < 4; ++i) {
            int row = r0 + lq * 4 + i;
            if (row >= NN) continue;
            float pr  = acc2[0 * 8 + j][i] + cbr;
            float pz  = acc2[1 * 8 + j][i] + cbz;
            float pin = acc2[2 * 8 + j][i] + cbn;
            float phn = acc2[3 * 8 + j][i] + cbh;
            float r = 1.f / (1.f + expf(-pr));
            float z = 1.f / (1.f + expf(-pz));
            float nv = tanhf(pin + r * phn);
            float hold = hf[(size_t)row * DD + d];
            float hnew = (1.f - z) * nv + z * hold;
            hf[(size_t)row * DD + d] = hnew;
            hbn[(size_t)row * DD + d] = (__bf16)hnew;
        }
    }
}

// ================= readout =================
__global__ void attn_kernel(const float* __restrict__ hf, const float* __restrict__ w_gate,
                            const float* __restrict__ b_gate, float* __restrict__ attn) {
    int node = blockIdx.x * 4 + (threadIdx.x >> 6);
    int lane = threadIdx.x & 63;
    if (node >= NN) return;
    size_t base = (size_t)node * DD;
    float s = hf[base + lane * 2] * w_gate[lane * 2]
            + hf[base + lane * 2 + 1] * w_gate[lane * 2 + 1];
    for (int off = 32; off; off >>= 1) s += __shfl_down(s, off);
    if (lane == 0) attn[node] = 1.f / (1.f + expf(-(s + b_gate[0])));
}

__global__ void segsum_kernel(const int* __restrict__ goff, const float* __restrict__ attn,
                              const float* __restrict__ hf, float* __restrict__ sg,
                              float* __restrict__ asumg) {
    int g = blockIdx.x;
    int d = threadIdx.x;
    int beg = goff[g], end = goff[g + 1];
    float s = 0.f, asum = 0.f;
    for (int i = beg; i < end; ++i) {
        float a = attn[i];
        s += a * hf[(size_t)i * DD + d];
        if (d == 0) asum += a;
    }
    sg[g * DD + d] = s;
    if (d == 0) asumg[g] = asum;
}

__global__ void readout_kernel(const float* __restrict__ sg, const float* __restrict__ asumg,
                               const float* __restrict__ W_g, const float* __restrict__ b_g,
                               float* __restrict__ hgraph) {
    int g = blockIdx.x;
    int m = threadIdx.x;
    float acc = asumg[g] * b_g[m];
    for (int d = 0; d < DD; ++d) acc += sg[g * DD + d] * W_g[d * GHID + m];
    hgraph[g * GHID + m] = acc;
}

// ================= launch =================
extern "C" void kernel_launch(void* const* d_in, const int* in_sizes, int n_in,
                              void* d_out, int out_size, void* d_ws, size_t ws_size,
                              hipStream_t stream) {
    const int*   node_types = (const int*)d_in[0];
    const int*   edge_src   = (const int*)d_in[1];
    const int*   edge_dst   = (const int*)d_in[2];
    const int*   edge_type  = (const int*)d_in[3];
    const int*   node2graph = (const int*)d_in[4];
    const float* emb        = (const float*)d_in[5];
    const float* W_msg      = (const float*)d_in[6];
    const float* b_msg      = (const float*)d_in[7];
    const float* W_ih       = (const float*)d_in[8];
    const float* W_hh       = (const float*)d_in[9];
    const float* b_ih       = (const float*)d_in[10];
    const float* b_hh       = (const float*)d_in[11];
    const float* w_gate     = (const float*)d_in[12];
    const float* b_gate     = (const float*)d_in[13];
    const float* W_g        = (const float*)d_in[14];
    const float* b_g        = (const float*)d_in[15];

    float* hf     = (float*)d_out;
    float* hgraph = hf + (size_t)NN * DD;

    char* ws = (char*)d_ws;
    size_t off = 0;
    auto alloc = [&](size_t bytes) -> char* {
        char* p = ws + off;
        off += (bytes + 255) & ~(size_t)255;
        return p;
    };
    __bf16* X       = (__bf16*)alloc((size_t)NN * 512 * 2);   // 51.2 MB
    __bf16* hb0     = (__bf16*)alloc((size_t)NN * DD * 2);    // 12.8 MB
    __bf16* hb1     = (__bf16*)alloc((size_t)NN * DD * 2);    // 12.8 MB
    __bf16* WK      = (__bf16*)alloc((size_t)16 * 4 * 256 * 8 * 2);
    __bf16* WB      = (__bf16*)alloc((size_t)12 * 4 * 512 * 8 * 2);
    float*  b512    = (float*)alloc(512 * 4);
    float*  attn    = (float*)alloc((size_t)NN * 4);
    float*  sg      = (float*)alloc((size_t)NG * DD * 4);
    float*  asumg   = (float*)alloc((size_t)NG * 4);
    int*    counts  = (int*)alloc((size_t)(NKEY + 1) * 4);
    int*    offsets = (int*)alloc((size_t)(NKEY + 1) * 4);
    int*    cursor  = (int*)alloc((size_t)(NKEY + 1) * 4);
    int*    bsum    = (int*)alloc((size_t)1024 * 4);
    int*    elist   = (int*)alloc((size_t)NE * 4);
    int*    gcounts = (int*)alloc((size_t)(NG + 1) * 4);
    int*    goff    = (int*)alloc((size_t)(NG + 1) * 4);
    int*    gbsum   = (int*)alloc((size_t)8 * 4);

    hipMemsetAsync(counts, 0, (NKEY + 1) * 4, stream);
    hipMemsetAsync(gcounts, 0, (NG + 1) * 4, stream);

    build_WK<<<(16 * 4 * 256 * 8 + 255) / 256, 256, 0, stream>>>(W_msg, WK);
    build_WB<<<(12 * 4 * 512 * 8 + 255) / 256, 256, 0, stream>>>(W_ih, W_hh, WB);
    build_bias512<<<2, 256, 0, stream>>>(b_ih, b_hh, b512);
    embed_kernel<<<(NN * DD + 255) / 256, 256, 0, stream>>>(node_types, emb, hf, hb0);

    int nbE = (NKEY + 255) / 256;
    hist_kernel<<<(NE + 255) / 256, 256, 0, stream>>>(edge_src, edge_type, counts);
    scan1<<<nbE, 256, 0, stream>>>(counts, offsets, bsum, NKEY);
    scan2<<<1, 1024, 0, stream>>>(bsum, nbE, offsets, NKEY);
    scan3<<<nbE, 256, 0, stream>>>(offsets, bsum, cursor, NKEY);
    fill_kernel<<<(NE + 255) / 256, 256, 0, stream>>>(edge_src, edge_dst, edge_type, cursor, elist);

    int nbG = (NG + 255) / 256;
    ghist_kernel<<<(NN + 255) / 256, 256, 0, stream>>>(node2graph, gcounts);
    scan1<<<nbG, 256, 0, stream>>>(gcounts, goff, gbsum, NG);
    scan2<<<1, 1024, 0, stream>>>(gbsum, nbG, goff, NG);
    scan3<<<nbG, 256, 0, stream>>>(goff, gbsum, (int*)nullptr, NG);

    int rt = (NN + 63) / 64;  // 782
    __bf16* hbc = hb0;
    __bf16* hbn = hb1;
    for (int p = 0; p < NPASS; ++p) {
        agg4<<<(NKEY + 3) / 4, 256, 0, stream>>>(offsets, elist, hbc, X);
        mg_gemm2<<<rt, 256, 0, stream>>>(X, WK, WB, b_msg, b512, offsets, hbc, hf, hbn);
        __bf16* t = hbc; hbc = hbn; hbn = t;
    }

    attn_kernel<<<(NN + 3) / 4, 256, 0, stream>>>(hf, w_gate, b_gate, attn);
    segsum_kernel<<<NG, 128, 0, stream>>>(goff, attn, hf, sg, asumg);
    readout_kernel<<<NG, GHID, 0, stream>>>(sg, asumg, W_g, b_g, hgraph);
}

// Round 11
// 907.745 us; speedup vs baseline: 1.6675x; 1.6675x over previous
//
#include <hip/hip_runtime.h>
#include <hip/hip_bf16.h>

#define NN 50000
#define NE 800000
#define NG 512
#define DD 128
#define MM 256
#define TT 4
#define NPASS 4
#define GHID 256
#define NKEY (NN * TT)          // CSR keys: src*4 + type

typedef __bf16 bf16x2 __attribute__((ext_vector_type(2)));
typedef __bf16 bf16x8 __attribute__((ext_vector_type(8)));
typedef float f32x4 __attribute__((ext_vector_type(4)));

// ================= setup: swizzled weights =================
// WK: msgs GEMM B, K=512 in 16 chunks: WK[((c*4+lq)*256+col)*8+j] = W_msg[((c*4+lq)*8+j)*256+col]
__global__ void build_WK(const float* __restrict__ W_msg, __bf16* __restrict__ WK) {
    int i = blockIdx.x * 256 + threadIdx.x;           // 131072
    if (i >= 16 * 4 * 256 * 8) return;
    int j = i & 7, col = (i >> 3) & 255, g = i >> 11; // g=c*4+lq
    int k = g * 8 + j;
    WK[i] = (__bf16)W_msg[k * 256 + col];
}

// WB: 512 cols x K=384 (12 chunks). cols [0,128)=r, [128,256)=z (Wih+Whh stacked over k),
// [256,384)=i_n (Wih only), [384,512)=h_n (Whh only). k<256 -> msgs, k>=256 -> hb.
__global__ void build_WB(const float* __restrict__ W_ih, const float* __restrict__ W_hh,
                         __bf16* __restrict__ WB) {
    int i = blockIdx.x * 256 + threadIdx.x;           // 196608
    if (i >= 12 * 4 * 512 * 8) return;
    int j = i & 7, col = (i >> 3) & 511, g = i >> 12; // g=c*4+lq
    int k = g * 8 + j;                                // 0..383
    float v = 0.f;
    if (col < 256) {
        v = (k < 256) ? W_ih[col * 256 + k] : W_hh[col * 128 + (k - 256)];
    } else if (col < 384) {
        if (k < 256) v = W_ih[col * 256 + k];
    } else {
        if (k >= 256) v = W_hh[(col - 128) * 128 + (k - 256)];
    }
    WB[i] = (__bf16)v;
}

__global__ void build_bias512(const float* __restrict__ b_ih, const float* __restrict__ b_hh,
                              float* __restrict__ b512) {
    int c = blockIdx.x * 256 + threadIdx.x;
    if (c >= 512) return;
    float v;
    if (c < 256) v = b_ih[c] + b_hh[c];
    else if (c < 384) v = b_ih[c];
    else v = b_hh[c - 128];
    b512[c] = v;
}

// ================= embedding =================
__global__ void embed_kernel(const int* __restrict__ node_types,
                             const float* __restrict__ emb,
                             float* __restrict__ hf, __bf16* __restrict__ hb) {
    int t = blockIdx.x * 256 + threadIdx.x;
    if (t >= NN * DD) return;
    int node = t >> 7, d = t & 127;
    float v = emb[node_types[node] * DD + d];
    hf[t] = v;
    hb[t] = (__bf16)v;
}

// ================= CSR build (keyed by src*4+type) =================
__global__ void hist_kernel(const int* __restrict__ src, const int* __restrict__ et,
                            int* __restrict__ counts) {
    int e = blockIdx.x * 256 + threadIdx.x;
    if (e < NE) atomicAdd(&counts[src[e] * TT + et[e]], 1);
}

__global__ void ghist_kernel(const int* __restrict__ n2g, int* __restrict__ gcounts) {
    int i = blockIdx.x * 256 + threadIdx.x;
    if (i < NN) atomicAdd(&gcounts[n2g[i]], 1);
}

__global__ void scan1(const int* __restrict__ counts, int* __restrict__ offsets,
                      int* __restrict__ bsum, int n) {
    __shared__ int sm[256];
    int i = blockIdx.x * 256 + threadIdx.x;
    int v = (i < n) ? counts[i] : 0;
    sm[threadIdx.x] = v;
    __syncthreads();
    for (int off = 1; off < 256; off <<= 1) {
        int t = (threadIdx.x >= off) ? sm[threadIdx.x - off] : 0;
        __syncthreads();
        sm[threadIdx.x] += t;
        __syncthreads();
    }
    if (i < n) offsets[i] = sm[threadIdx.x] - v;
    if (threadIdx.x == 255) bsum[blockIdx.x] = sm[255];
}

__global__ void scan2(int* __restrict__ bsum, int nb, int* __restrict__ offsets, int n) {
    __shared__ int sm[1024];
    int v = (threadIdx.x < nb) ? bsum[threadIdx.x] : 0;
    sm[threadIdx.x] = v;
    __syncthreads();
    for (int off = 1; off < 1024; off <<= 1) {
        int t = (threadIdx.x >= off) ? sm[threadIdx.x - off] : 0;
        __syncthreads();
        sm[threadIdx.x] += t;
        __syncthreads();
    }
    if (threadIdx.x < nb) bsum[threadIdx.x] = sm[threadIdx.x] - v;
    if (threadIdx.x == 1023) offsets[n] = sm[1023];
}

__global__ void scan3(int* __restrict__ offsets, const int* __restrict__ bsum,
                      int* __restrict__ cursor, int n) {
    int i = blockIdx.x * 256 + threadIdx.x;
    if (i < n) {
        int o = offsets[i] + bsum[blockIdx.x];
        offsets[i] = o;
        if (cursor) cursor[i] = o;
    }
}

__global__ void fill_kernel(const int* __restrict__ src, const int* __restrict__ dst,
                            const int* __restrict__ et, int* __restrict__ cursor,
                            int* __restrict__ elist) {
    int e = blockIdx.x * 256 + threadIdx.x;
    if (e >= NE) return;
    int pos = atomicAdd(&cursor[src[e] * TT + et[e]], 1);
    elist[pos] = dst[e];
}

// ================= aggregation: wave per key, 8 concurrent gathers =================
__global__ void agg4(const int* __restrict__ offsets, const int* __restrict__ elist,
                     const __bf16* __restrict__ hb, __bf16* __restrict__ X) {
    int w = blockIdx.x * 4 + (threadIdx.x >> 6);
    if (w >= NKEY) return;
    int lane = threadIdx.x & 63;
    int beg = offsets[w], end = offsets[w + 1];
    float ax = 0.f, ay = 0.f;
    for (int base = beg; base < end; base += 8) {
        int nb = end - base; if (nb > 8) nb = 8;          // wave-uniform
        int idx = (lane < nb) ? elist[base + lane] : 0;
        int i0 = __shfl(idx, 0), i1 = __shfl(idx, 1), i2 = __shfl(idx, 2), i3 = __shfl(idx, 3);
        int i4 = __shfl(idx, 4), i5 = __shfl(idx, 5), i6 = __shfl(idx, 6), i7 = __shfl(idx, 7);
        size_t col = lane * 2;
        bf16x2 v0, v1, v2, v3, v4, v5, v6, v7;
        v0 = *(const bf16x2*)(hb + (size_t)i0 * DD + col);
        if (nb > 1) v1 = *(const bf16x2*)(hb + (size_t)i1 * DD + col);
        if (nb > 2) v2 = *(const bf16x2*)(hb + (size_t)i2 * DD + col);
        if (nb > 3) v3 = *(const bf16x2*)(hb + (size_t)i3 * DD + col);
        if (nb > 4) v4 = *(const bf16x2*)(hb + (size_t)i4 * DD + col);
        if (nb > 5) v5 = *(const bf16x2*)(hb + (size_t)i5 * DD + col);
        if (nb > 6) v6 = *(const bf16x2*)(hb + (size_t)i6 * DD + col);
        if (nb > 7) v7 = *(const bf16x2*)(hb + (size_t)i7 * DD + col);
        ax += (float)v0.x; ay += (float)v0.y;
        if (nb > 1) { ax += (float)v1.x; ay += (float)v1.y; }
        if (nb > 2) { ax += (float)v2.x; ay += (float)v2.y; }
        if (nb > 3) { ax += (float)v3.x; ay += (float)v3.y; }
        if (nb > 4) { ax += (float)v4.x; ay += (float)v4.y; }
        if (nb > 5) { ax += (float)v5.x; ay += (float)v5.y; }
        if (nb > 6) { ax += (float)v6.x; ay += (float)v6.y; }
        if (nb > 7) { ax += (float)v7.x; ay += (float)v7.y; }
    }
    bf16x2 o; o.x = (__bf16)ax; o.y = (__bf16)ay;
    *(bf16x2*)(X + (size_t)w * 128 + lane * 2) = o;
}

// ================= fused msgs+GRU GEMM with LDS weight staging =================
// grid 782 x 256 thr (4 waves, 64 rows). launch_bounds(256,2): up to 256 VGPR — the 32-acc
// phase-2 working set (~200 regs) fits with NO spill (R10 spilled at the default 64-VGPR cap).
__global__ void __launch_bounds__(256, 2)
mg_gemm2(const __bf16* __restrict__ X, const __bf16* __restrict__ WK,
         const __bf16* __restrict__ WB, const float* __restrict__ b_msg,
         const float* __restrict__ b512, const int* __restrict__ offsets,
         const __bf16* __restrict__ hbc, float* __restrict__ hf,
         __bf16* __restrict__ hbn) {
    __shared__ __bf16 Ms[4][16][264];   // 33 KB wave-private msgs tiles
    __shared__ __bf16 Ws[16384];        // 32 KB weight-chunk stage
    int tid = threadIdx.x, wave = tid >> 6, lane = tid & 63;
    int lm = lane & 15, lq = lane >> 4;
    int r0 = blockIdx.x * 64 + wave * 16;
    int arow = r0 + lm; if (arow >= NN) arow = NN - 1;

    // ---- phase 1: msgs tile (K=512, 16 chunks; WK chunk = 8192 elems staged) ----
    {
        const __bf16* Ap = X + (size_t)arow * 512 + lq * 8;
        f32x4 acc[16] = {};
        for (int c = 0; c < 16; ++c) {
            const __bf16* src = WK + (size_t)c * 8192;
            bf16x8 t0 = *(const bf16x8*)(src + tid * 8);
            bf16x8 t1 = *(const bf16x8*)(src + 2048 + tid * 8);
            bf16x8 t2 = *(const bf16x8*)(src + 4096 + tid * 8);
            bf16x8 t3 = *(const bf16x8*)(src + 6144 + tid * 8);
            bf16x8 a = *(const bf16x8*)(Ap + c * 32);
            __syncthreads();               // prev chunk consumed
            *(bf16x8*)&Ws[tid * 8]        = t0;
            *(bf16x8*)&Ws[2048 + tid * 8] = t1;
            *(bf16x8*)&Ws[4096 + tid * 8] = t2;
            *(bf16x8*)&Ws[6144 + tid * 8] = t3;
            __syncthreads();               // chunk visible
#pragma unroll
            for (int nt = 0; nt < 16; ++nt) {
                bf16x8 b = *(const bf16x8*)&Ws[((size_t)lq * 256 + nt * 16 + lm) * 8];
                acc[nt] = __builtin_amdgcn_mfma_f32_16x16x32_bf16(a, b, acc[nt], 0, 0, 0);
            }
        }
#pragma unroll
        for (int i = 0; i < 4; ++i) {
            int row = r0 + lq * 4 + i;
            int rowc = (row < NN) ? row : NN - 1;
            int ob = rowc * TT;
            int o0 = offsets[ob], o1 = offsets[ob + 1], o2 = offsets[ob + 2],
                o3 = offsets[ob + 3], o4 = offsets[ob + 4];
            float n0 = (float)(o1 - o0), n1 = (float)(o2 - o1),
                  n2 = (float)(o3 - o2), n3 = (float)(o4 - o3);
#pragma unroll
            for (int nt = 0; nt < 16; ++nt) {
                int col = nt * 16 + lm;
                float bias = n0 * b_msg[col] + n1 * b_msg[MM + col]
                           + n2 * b_msg[2 * MM + col] + n3 * b_msg[3 * MM + col];
                Ms[wave][lq * 4 + i][col] = (__bf16)fmaxf(acc[nt][i] + bias, 0.f);
            }
        }
    }

    // ---- phase 2: GRU GEMM, c-outer (12 chunks; WB chunk = 16384 elems staged), 32 acc ----
    bf16x8 ahb[4];
    {
        const __bf16* Ah = hbc + (size_t)arow * DD + lq * 8;
#pragma unroll
        for (int c4 = 0; c4 < 4; ++c4) ahb[c4] = *(const bf16x8*)(Ah + c4 * 32);
    }
    f32x4 acc2[32] = {};   // [gate g][j]: g*8+j
    for (int c = 0; c < 12; ++c) {
        const __bf16* src = WB + (size_t)c * 16384;
        bf16x8 t0 = *(const bf16x8*)(src + tid * 8);
        bf16x8 t1 = *(const bf16x8*)(src + 2048 + tid * 8);
        bf16x8 t2 = *(const bf16x8*)(src + 4096 + tid * 8);
        bf16x8 t3 = *(const bf16x8*)(src + 6144 + tid * 8);
        bf16x8 t4 = *(const bf16x8*)(src + 8192 + tid * 8);
        bf16x8 t5 = *(const bf16x8*)(src + 10240 + tid * 8);
        bf16x8 t6 = *(const bf16x8*)(src + 12288 + tid * 8);
        bf16x8 t7 = *(const bf16x8*)(src + 14336 + tid * 8);
        bf16x8 a = (c < 8) ? *(const bf16x8*)&Ms[wave][lm][c * 32 + lq * 8] : ahb[c - 8];
        __syncthreads();
        *(bf16x8*)&Ws[tid * 8]         = t0;
        *(bf16x8*)&Ws[2048 + tid * 8]  = t1;
        *(bf16x8*)&Ws[4096 + tid * 8]  = t2;
        *(bf16x8*)&Ws[6144 + tid * 8]  = t3;
        *(bf16x8*)&Ws[8192 + tid * 8]  = t4;
        *(bf16x8*)&Ws[10240 + tid * 8] = t5;
        *(bf16x8*)&Ws[12288 + tid * 8] = t6;
        *(bf16x8*)&Ws[14336 + tid * 8] = t7;
        __syncthreads();
#pragma unroll
        for (int j = 0; j < 8; ++j) {
#pragma unroll
            for (int g = 0; g < 4; ++g) {
                bf16x8 b = *(const bf16x8*)&Ws[((size_t)lq * 512 + g * 128 + j * 16 + lm) * 8];
                acc2[g * 8 + j] = __builtin_amdgcn_mfma_f32_16x16x32_bf16(a, b, acc2[g * 8 + j], 0, 0, 0);
            }
        }
    }
    // ---- epilogue: GRU gates ----
#pragma unroll
    for (int j = 0; j < 8; ++j) {
        int d = j * 16 + lm;
        float cbr = b512[d], cbz = b512[128 + d], cbn = b512[256 + d], cbh = b512[384 + d];
#pragma unroll
        for (int i = 0; i < 4; ++i) {
            int row = r0 + lq * 4 + i;
            if (row >= NN) continue;
            float pr  = acc2[0 * 8 + j][i] + cbr;
            float pz  = acc2[1 * 8 + j][i] + cbz;
            float pin = acc2[2 * 8 + j][i] + cbn;
            float phn = acc2[3 * 8 + j][i] + cbh;
            float r = 1.f / (1.f + expf(-pr));
            float z = 1.f / (1.f + expf(-pz));
            float nv = tanhf(pin + r * phn);
            float hold = hf[(size_t)row * DD + d];
            float hnew = (1.f - z) * nv + z * hold;
            hf[(size_t)row * DD + d] = hnew;
            hbn[(size_t)row * DD + d] = (__bf16)hnew;
        }
    }
}

// ================= readout =================
__global__ void attn_kernel(const float* __restrict__ hf, const float* __restrict__ w_gate,
                            const float* __restrict__ b_gate, float* __restrict__ attn) {
    int node = blockIdx.x * 4 + (threadIdx.x >> 6);
    int lane = threadIdx.x & 63;
    if (node >= NN) return;
    size_t base = (size_t)node * DD;
    float s = hf[base + lane * 2] * w_gate[lane * 2]
            + hf[base + lane * 2 + 1] * w_gate[lane * 2 + 1];
    for (int off = 32; off; off >>= 1) s += __shfl_down(s, off);
    if (lane == 0) attn[node] = 1.f / (1.f + expf(-(s + b_gate[0])));
}

__global__ void segsum_kernel(const int* __restrict__ goff, const float* __restrict__ attn,
                              const float* __restrict__ hf, float* __restrict__ sg,
                              float* __restrict__ asumg) {
    int g = blockIdx.x;
    int d = threadIdx.x;
    int beg = goff[g], end = goff[g + 1];
    float s = 0.f, asum = 0.f;
    for (int i = beg; i < end; ++i) {
        float a = attn[i];
        s += a * hf[(size_t)i * DD + d];
        if (d == 0) asum += a;
    }
    sg[g * DD + d] = s;
    if (d == 0) asumg[g] = asum;
}

__global__ void readout_kernel(const float* __restrict__ sg, const float* __restrict__ asumg,
                               const float* __restrict__ W_g, const float* __restrict__ b_g,
                               float* __restrict__ hgraph) {
    int g = blockIdx.x;
    int m = threadIdx.x;
    float acc = asumg[g] * b_g[m];
    for (int d = 0; d < DD; ++d) acc += sg[g * DD + d] * W_g[d * GHID + m];
    hgraph[g * GHID + m] = acc;
}

// ================= launch =================
extern "C" void kernel_launch(void* const* d_in, const int* in_sizes, int n_in,
                              void* d_out, int out_size, void* d_ws, size_t ws_size,
                              hipStream_t stream) {
    const int*   node_types = (const int*)d_in[0];
    const int*   edge_src   = (const int*)d_in[1];
    const int*   edge_dst   = (const int*)d_in[2];
    const int*   edge_type  = (const int*)d_in[3];
    const int*   node2graph = (const int*)d_in[4];
    const float* emb        = (const float*)d_in[5];
    const float* W_msg      = (const float*)d_in[6];
    const float* b_msg      = (const float*)d_in[7];
    const float* W_ih       = (const float*)d_in[8];
    const float* W_hh       = (const float*)d_in[9];
    const float* b_ih       = (const float*)d_in[10];
    const float* b_hh       = (const float*)d_in[11];
    const float* w_gate     = (const float*)d_in[12];
    const float* b_gate     = (const float*)d_in[13];
    const float* W_g        = (const float*)d_in[14];
    const float* b_g        = (const float*)d_in[15];

    float* hf     = (float*)d_out;
    float* hgraph = hf + (size_t)NN * DD;

    char* ws = (char*)d_ws;
    size_t off = 0;
    auto alloc = [&](size_t bytes) -> char* {
        char* p = ws + off;
        off += (bytes + 255) & ~(size_t)255;
        return p;
    };
    __bf16* X       = (__bf16*)alloc((size_t)NN * 512 * 2);   // 51.2 MB
    __bf16* hb0     = (__bf16*)alloc((size_t)NN * DD * 2);    // 12.8 MB
    __bf16* hb1     = (__bf16*)alloc((size_t)NN * DD * 2);    // 12.8 MB
    __bf16* WK      = (__bf16*)alloc((size_t)16 * 4 * 256 * 8 * 2);
    __bf16* WB      = (__bf16*)alloc((size_t)12 * 4 * 512 * 8 * 2);
    float*  b512    = (float*)alloc(512 * 4);
    float*  attn    = (float*)alloc((size_t)NN * 4);
    float*  sg      = (float*)alloc((size_t)NG * DD * 4);
    float*  asumg   = (float*)alloc((size_t)NG * 4);
    int*    counts  = (int*)alloc((size_t)(NKEY + 1) * 4);
    int*    offsets = (int*)alloc((size_t)(NKEY + 1) * 4);
    int*    cursor  = (int*)alloc((size_t)(NKEY + 1) * 4);
    int*    bsum    = (int*)alloc((size_t)1024 * 4);
    int*    elist   = (int*)alloc((size_t)NE * 4);
    int*    gcounts = (int*)alloc((size_t)(NG + 1) * 4);
    int*    goff    = (int*)alloc((size_t)(NG + 1) * 4);
    int*    gbsum   = (int*)alloc((size_t)8 * 4);

    hipMemsetAsync(counts, 0, (NKEY + 1) * 4, stream);
    hipMemsetAsync(gcounts, 0, (NG + 1) * 4, stream);

    build_WK<<<(16 * 4 * 256 * 8 + 255) / 256, 256, 0, stream>>>(W_msg, WK);
    build_WB<<<(12 * 4 * 512 * 8 + 255) / 256, 256, 0, stream>>>(W_ih, W_hh, WB);
    build_bias512<<<2, 256, 0, stream>>>(b_ih, b_hh, b512);
    embed_kernel<<<(NN * DD + 255) / 256, 256, 0, stream>>>(node_types, emb, hf, hb0);

    int nbE = (NKEY + 255) / 256;
    hist_kernel<<<(NE + 255) / 256, 256, 0, stream>>>(edge_src, edge_type, counts);
    scan1<<<nbE, 256, 0, stream>>>(counts, offsets, bsum, NKEY);
    scan2<<<1, 1024, 0, stream>>>(bsum, nbE, offsets, NKEY);
    scan3<<<nbE, 256, 0, stream>>>(offsets, bsum, cursor, NKEY);
    fill_kernel<<<(NE + 255) / 256, 256, 0, stream>>>(edge_src, edge_dst, edge_type, cursor, elist);

    int nbG = (NG + 255) / 256;
    ghist_kernel<<<(NN + 255) / 256, 256, 0, stream>>>(node2graph, gcounts);
    scan1<<<nbG, 256, 0, stream>>>(gcounts, goff, gbsum, NG);
    scan2<<<1, 1024, 0, stream>>>(gbsum, nbG, goff, NG);
    scan3<<<nbG, 256, 0, stream>>>(goff, gbsum, (int*)nullptr, NG);

    int rt = (NN + 63) / 64;  // 782
    __bf16* hbc = hb0;
    __bf16* hbn = hb1;
    for (int p = 0; p < NPASS; ++p) {
        agg4<<<(NKEY + 3) / 4, 256, 0, stream>>>(offsets, elist, hbc, X);
        mg_gemm2<<<rt, 256, 0, stream>>>(X, WK, WB, b_msg, b512, offsets, hbc, hf, hbn);
        __bf16* t = hbc; hbc = hbn; hbn = t;
    }

    attn_kernel<<<(NN + 3) / 4, 256, 0, stream>>>(hf, w_gate, b_gate, attn);
    segsum_kernel<<<NG, 128, 0, stream>>>(goff, attn, hf, sg, asumg);
    readout_kernel<<<NG, GHID, 0, stream>>>(sg, asumg, W_g, b_g, hgraph);
}